// Round 3
// baseline (223.370 us; speedup 1.0000x reference)
//
#include <hip/hip_runtime.h>
#include <hip/hip_fp16.h>
#include <stdint.h>

// LightGCNConv: out[row] += x[col] * edge_weight[e]
// x:[N,64] f32, edge_index:[2,E] int32, edge_weight:[E] f32, out:[N,64] f32.
//
// Pipeline (v4 — split buckets for occupancy, decontended reservations):
//  1) prep: merged {x->bf16 convert | edge binning} by block range.
//     Binning: CHUNK=8192 edges/block via int4/float4 loads, LDS histogram,
//     ONE global atomicAdd per (block,bucket) into a 64B-PADDED counter
//     (v3 packed counters = 49 contended lines), dense 8B run stores.
//  2) bucket_acc: SPLIT=4 blocks per 128-row bucket (grid ~3128 = 12/CU;
//     v3's 782 = 3/CU gave 43% occupancy). Each sub-block accumulates its
//     segment slice into a 32KB fixed-point LDS tile (native ds_add_u32),
//     then combines with native global_atomic_add_f32 into pre-zeroed out.

typedef unsigned long long ull;
typedef int   v4i __attribute__((ext_vector_type(4)));
typedef float v4f __attribute__((ext_vector_type(4)));

#define RB      128      // rows per bucket
#define CAP     2432     // entries per bucket segment; mean 2048 (+8.5 sigma)
#define CHUNK   8192     // edges per bin block (512 thr x 16)
#define SPLIT   4        // blocks per bucket in bucket_acc
#define BPAD    16       // bcnt stride in ints (64B: one counter per line)
#define OVF_CAP 65536
#define MAXNB   1024     // max buckets (N <= 131072)

#define FXS     65536.0f
#define FXSI    (1.0f / 65536.0f)

__device__ __forceinline__ unsigned short f2bf(float f) {
    union { float f; unsigned int u; } c;
    c.f = f;
    unsigned int lsb = (c.u >> 16) & 1u;
    c.u += 0x7fffu + lsb;
    return (unsigned short)(c.u >> 16);
}
__device__ __forceinline__ float bf2f(unsigned short u) {
    union { unsigned int u; float f; } c;
    c.u = ((unsigned int)u) << 16;
    return c.f;
}

// ---------- phase 1 (merged): edge binning | x->bf16 convert ----------
__global__ __launch_bounds__(512) void prep(
    const int* __restrict__ ei, const float* __restrict__ ew,
    int* __restrict__ bcnt, ull* __restrict__ seg,
    int* __restrict__ ovf_cnt, int3* __restrict__ ovf, int E, int NB,
    int nbin, const float* __restrict__ x, unsigned short* __restrict__ xb,
    int n4)
{
    __shared__ int hist[MAXNB];
    __shared__ int gbase[MAXNB];
    int t = threadIdx.x;

    if ((int)blockIdx.x >= nbin) {
        // ---- convert part: 2048 v4f per block ----
        int i0 = ((int)blockIdx.x - nbin) * 2048 + t;
#pragma unroll
        for (int k = 0; k < 4; ++k) {
            int i = i0 + k * 512;
            if (i < n4) {
                v4f v = ((const v4f*)x)[i];
                ushort4 o;
                o.x = f2bf(v.x); o.y = f2bf(v.y);
                o.z = f2bf(v.z); o.w = f2bf(v.w);
                ((ushort4*)xb)[i] = o;
            }
        }
        return;
    }

    // ---- bin part ----
    for (int i = t; i < NB; i += 512) hist[i] = 0;
    __syncthreads();

    int e0 = blockIdx.x * CHUNK;
    bool al4 = ((E & 3) == 0);

    unsigned pk[16];   // lpos<<10 | bkt
    ull      cw[16];   // w<<32 | rl<<17 | col
    bool     vd[16];
#pragma unroll
    for (int j = 0; j < 4; ++j) {
        int eb = e0 + (j * 512 + t) * 4;
        v4i r4, c4; v4f w4;
        if (al4 && eb + 3 < E) {
            r4 = *(const v4i*)(ei + eb);
            c4 = *(const v4i*)(ei + E + eb);
            w4 = *(const v4f*)(ew + eb);
        } else {
#pragma unroll
            for (int u = 0; u < 4; ++u) {
                int e = eb + u;
                r4[u] = e < E ? ei[e] : 0;
                c4[u] = e < E ? ei[E + e] : 0;
                w4[u] = e < E ? ew[e] : 0.f;
            }
        }
#pragma unroll
        for (int u = 0; u < 4; ++u) {
            int idx = j * 4 + u;
            int e = eb + u;
            vd[idx] = e < E;
            int bkt = r4[u] >> 7;
            int rl  = r4[u] & 127;
            int lp = 0;
            if (vd[idx]) lp = atomicAdd(&hist[bkt], 1);   // native LDS atomic
            pk[idx] = (((unsigned)lp) << 10) | (unsigned)bkt;
            cw[idx] = (((ull)__float_as_uint(w4[u])) << 32) |
                      (unsigned)((rl << 17) | c4[u]);
        }
    }
    __syncthreads();

    // one global reservation per (block,bucket); padded counters so each
    // bucket's counter owns a full line -> no cross-bucket line contention
    for (int i = t; i < NB; i += 512) {
        int h = hist[i];
        gbase[i] = h ? atomicAdd(&bcnt[i * BPAD], h) : 0;
    }
    __syncthreads();

#pragma unroll
    for (int j = 0; j < 16; ++j) {
        if (!vd[j]) continue;
        int bkt = pk[j] & 1023;
        int pos = gbase[bkt] + (int)(pk[j] >> 10);
        if (pos < CAP) {
            seg[(size_t)bkt * CAP + pos] = cw[j];
        } else {
            int o = atomicAdd(ovf_cnt, 1);
            if (o < OVF_CAP) {
                unsigned lo = (unsigned)cw[j];
                ovf[o] = make_int3((bkt << 7) | ((lo >> 17) & 127),
                                   lo & 0x1FFFF, (int)(cw[j] >> 32));
            }
        }
    }
}

// ---------- phase 2: bucket slice -> LDS int tile -> atomic out ----------
// SPLIT blocks per bucket; block b handles bucket b%NB, slice b/NB.
template <bool BF>
__global__ __launch_bounds__(512, 8) void bucket_acc(
    const void* __restrict__ xv, const ull* __restrict__ seg,
    const int* __restrict__ bcnt, float* __restrict__ out, int N, int NB)
{
    __shared__ int acc[RB * 64];          // 32 KB, fixed-point 16.16
    int t = threadIdx.x;
    int b = blockIdx.x;
    int g = b % NB;
    int s = b / NB;

#pragma unroll
    for (int i = 0; i < (RB * 16) / 512; ++i)
        ((v4i*)acc)[t + i * 512] = (v4i){0, 0, 0, 0};
    __syncthreads();

    int c = bcnt[g * BPAD];
    if (c > CAP) c = CAP;
    int plo = (int)(((long long)c * s) / SPLIT);
    int phi = (int)(((long long)c * (s + 1)) / SPLIT);

    const ull* base = seg + (size_t)g * CAP;
    int wid  = t >> 6;
    int lane = t & 63;
    const unsigned short* xh = (const unsigned short*)xv;
    const float*          xf = (const float*)xv;

    // 8 waves, interleaved groups of 8, 8-deep pipelined gathers
    for (int p0 = plo + wid * 8; p0 < phi; p0 += 8 * 8) {
        ull e[8]; float xr[8], wv[8]; int rl[8];
#pragma unroll
        for (int i = 0; i < 8; ++i) {
            int q = p0 + i;
            bool v = q < phi;
            if (!v) q = p0;                       // p0 < phi guaranteed
            e[i]  = base[q];                      // wave-uniform load
            wv[i] = v ? __int_as_float((int)(e[i] >> 32)) : 0.0f;
        }
#pragma unroll
        for (int i = 0; i < 8; ++i) {
            unsigned lo = (unsigned)e[i];
            size_t off = (((size_t)(lo & 0x1FFFF)) << 6) + lane;
            xr[i] = BF ? bf2f(xh[off]) : xf[off];
            rl[i] = (lo >> 17) & (RB - 1);
        }
#pragma unroll
        for (int i = 0; i < 8; ++i) {
            int q = __float2int_rn(xr[i] * wv[i] * FXS);
            atomicAdd(&acc[(rl[i] << 6) + lane], q);   // native ds_add_u32
        }
    }
    __syncthreads();

    int row0 = g * RB;
    int rem  = N - row0;
    int nd   = (rem >= RB ? RB : rem) * 64;
    for (int i = t; i < nd; i += 512) {
        int a = acc[i];
        if (a)  // native global_atomic_add_f32, coalesced per wave
            atomicAdd(&out[(size_t)row0 * 64 + i], (float)a * FXSI);
    }
}

// ---------- overflow fixup (normally 0 edges) ----------
template <bool BF>
__global__ __launch_bounds__(256) void ovf_apply(
    const void* __restrict__ xv, const int* __restrict__ ovf_cnt,
    const int3* __restrict__ ovf, float* __restrict__ out)
{
    int n = *ovf_cnt;
    if (n > OVF_CAP) n = OVF_CAP;
    int wid  = (blockIdx.x * 256 + threadIdx.x) >> 6;
    int lane = threadIdx.x & 63;
    int nw   = gridDim.x * 4;
    for (int o = wid; o < n; o += nw) {
        int3 tt = ovf[o];
        float w = __int_as_float(tt.z);
        size_t off = (((size_t)tt.y) << 6) + lane;
        float x = BF ? bf2f(((const unsigned short*)xv)[off])
                     : ((const float*)xv)[off];
        atomicAdd(&out[(((size_t)tt.x) << 6) + lane], x * w);
    }
}

// ---------- fallback: direct atomic scatter ----------
__global__ __launch_bounds__(256) void scatter_edges(
    const float* __restrict__ x, const int* __restrict__ ei,
    const float* __restrict__ ew, float* __restrict__ out, int E)
{
    long long idx = (long long)blockIdx.x * 256 + threadIdx.x;
    int e = (int)(idx >> 4);
    if (e >= E) return;
    int j = (int)(idx & 15);
    int row = ei[e];
    int col = ei[E + e];
    float w = ew[e];
    v4f v = *(const v4f*)(x + (((size_t)col) << 6) + (j << 2));
    float* op = out + (((size_t)row) << 6) + (j << 2);
    atomicAdd(op + 0, v.x * w);
    atomicAdd(op + 1, v.y * w);
    atomicAdd(op + 2, v.z * w);
    atomicAdd(op + 3, v.w * w);
}

extern "C" void kernel_launch(void* const* d_in, const int* in_sizes, int n_in,
                              void* d_out, int out_size, void* d_ws, size_t ws_size,
                              hipStream_t stream) {
    const float* x  = (const float*)d_in[0];
    const int*   ei = (const int*)d_in[1];
    const float* ew = (const float*)d_in[2];
    float*       out = (float*)d_out;

    int E = in_sizes[2];
    int N = out_size / 64;
    int NB = (N + RB - 1) / RB;

    // ws (ints): bcnt[NB*BPAD] | ovf_cnt | pad | ovf[3*OVF] | [xb N*32] |
    //            seg[NB*CAP*2]
    size_t ovf_base  = (size_t)NB * BPAD + 2;
    size_t xb_base   = (ovf_base + 3 * (size_t)OVF_CAP + 3) & ~(size_t)3;
    size_t xb_ints   = (size_t)N * 32;
    size_t seg_ints  = (size_t)NB * CAP * 2;

    size_t seg_base_bf = (xb_base + xb_ints + 1) & ~(size_t)1;
    size_t need_bf     = (seg_base_bf + seg_ints) * 4;

    size_t seg_base_f  = (xb_base + 1) & ~(size_t)1;
    size_t need_f      = (seg_base_f + seg_ints) * 4;

    int nbin  = (E + CHUNK - 1) / CHUNK;
    int n4    = (N * 64) / 4;
    int nconv = (n4 + 2047) / 2048;

    if ((ws_size >= need_bf || ws_size >= need_f) && N <= (1 << 17)) {
        bool use_bf = ws_size >= need_bf;
        int* w32 = (int*)d_ws;
        int* bcnt = w32;
        int* ovf_cnt = w32 + NB * BPAD;
        int3* ovf = (int3*)(w32 + ovf_base);
        unsigned short* xb = (unsigned short*)(w32 + xb_base);
        ull* seg = (ull*)(w32 + (use_bf ? seg_base_bf : seg_base_f));

        (void)hipMemsetAsync(w32, 0, ((size_t)NB * BPAD + 2) * sizeof(int),
                             stream);
        (void)hipMemsetAsync(out, 0, (size_t)out_size * sizeof(float), stream);

        if (use_bf) {
            prep<<<nbin + nconv, 512, 0, stream>>>(
                ei, ew, bcnt, seg, ovf_cnt, ovf, E, NB, nbin, x, xb, n4);
            bucket_acc<true><<<NB * SPLIT, 512, 0, stream>>>(
                xb, seg, bcnt, out, N, NB);
            ovf_apply<true><<<64, 256, 0, stream>>>(xb, ovf_cnt, ovf, out);
        } else {
            prep<<<nbin, 512, 0, stream>>>(
                ei, ew, bcnt, seg, ovf_cnt, ovf, E, NB, nbin, x, xb, 0);
            bucket_acc<false><<<NB * SPLIT, 512, 0, stream>>>(
                x, seg, bcnt, out, N, NB);
            ovf_apply<false><<<64, 256, 0, stream>>>(x, ovf_cnt, ovf, out);
        }
    } else {
        (void)hipMemsetAsync(out, 0, (size_t)out_size * sizeof(float), stream);
        long long threads = (long long)E * 16;
        scatter_edges<<<(int)((threads + 255) / 256), 256, 0, stream>>>(
            x, ei, ew, out, E);
    }
}

// Round 4
// 196.091 us; speedup vs baseline: 1.1391x; 1.1391x over previous
//
#include <hip/hip_runtime.h>
#include <hip/hip_fp16.h>
#include <stdint.h>

// LightGCNConv: out[row] += x[col] * edge_weight[e]
// x:[N,64] f32, edge_index:[2,E] int32, edge_weight:[E] f32, out:[N,64] f32.
//
// Pipeline (v5 — LDS-CSR + register accumulation):
//  1) prep: merged {x->bf16 convert | edge binning into 64-row buckets}.
//     CHUNK=2048 edges/block (782 blocks = 3/CU for latency hiding; v3/v4
//     ran 391/195 blocks and bin cost ~90us by cross-round arithmetic).
//     LDS histogram, ONE padded-counter global atomicAdd per (block,bucket),
//     dense 8B run stores.
//  2) bucket_acc: per 64-row bucket: scatter segment into LDS padded-CSR
//     (int cursors + 4B packed col|fp16w entries, 12.3KB), then each wave
//     REGISTER-accumulates 16 rows via 8-deep pipelined gathers and stores
//     out coalesced. No per-edge LDS data atomics (v3: 94us), no global
//     atomic combine (v4: 111us, 98MB writes), no out pre-zero.
//     v1's row_acc (register acc) was 51us; this keeps that structure and
//     deletes its global CSR round-trip.

typedef unsigned long long ull;
typedef int   v4i __attribute__((ext_vector_type(4)));
typedef float v4f __attribute__((ext_vector_type(4)));

#define RB      64       // rows per bucket
#define CAP     1280     // entries per bucket segment; mean 1024 (+8 sigma)
#define CHUNK   2048     // edges per bin block (512 thr x 4)
#define SLOTS   48       // padded-CSR slots per row (max expected deg ~45)
#define BPAD    16       // bcnt stride in ints (64B: one counter per line)
#define OVF_CAP 65536
#define MAXNB   2048     // max buckets (N <= 131072)

__device__ __forceinline__ unsigned short f2bf(float f) {
    union { float f; unsigned int u; } c;
    c.f = f;
    unsigned int lsb = (c.u >> 16) & 1u;
    c.u += 0x7fffu + lsb;
    return (unsigned short)(c.u >> 16);
}
__device__ __forceinline__ float bf2f(unsigned short u) {
    union { unsigned int u; float f; } c;
    c.u = ((unsigned int)u) << 16;
    return c.f;
}
__device__ __forceinline__ unsigned pack_cw(int col, float w) {
    unsigned hb = __half_as_ushort(__float2half(w));
    return (((unsigned)col) << 15) | (hb >> 1);
}
__device__ __forceinline__ float unpack_w(unsigned v) {
    return __half2float(__ushort_as_half((unsigned short)((v & 0x7fffu) << 1)));
}

// ---------- phase 1 (merged): edge binning | x->bf16 convert ----------
__global__ __launch_bounds__(512) void prep(
    const int* __restrict__ ei, const float* __restrict__ ew,
    int* __restrict__ bcnt, ull* __restrict__ seg,
    int* __restrict__ ovf_cnt, int3* __restrict__ ovf, int E, int NB,
    int nbin, const float* __restrict__ x, unsigned short* __restrict__ xb,
    int n4)
{
    __shared__ int hist[MAXNB];
    __shared__ int gbase[MAXNB];
    int t = threadIdx.x;

    if ((int)blockIdx.x >= nbin) {
        // ---- convert part: 2048 v4f per block ----
        int i0 = ((int)blockIdx.x - nbin) * 2048 + t;
#pragma unroll
        for (int k = 0; k < 4; ++k) {
            int i = i0 + k * 512;
            if (i < n4) {
                v4f v = ((const v4f*)x)[i];
                ushort4 o;
                o.x = f2bf(v.x); o.y = f2bf(v.y);
                o.z = f2bf(v.z); o.w = f2bf(v.w);
                ((ushort4*)xb)[i] = o;
            }
        }
        return;
    }

    // ---- bin part: 4 edges/thread ----
    for (int i = t; i < NB; i += 512) hist[i] = 0;
    __syncthreads();

    int e0 = blockIdx.x * CHUNK;
    int eb = e0 + t * 4;
    bool al4 = ((E & 3) == 0);

    unsigned pk[4];   // lpos<<11 | bkt
    ull      cw[4];   // w<<32 | rl<<17 | col
    bool     vd[4];
    {
        v4i r4, c4; v4f w4;
        if (al4 && eb + 3 < E) {
            r4 = *(const v4i*)(ei + eb);
            c4 = *(const v4i*)(ei + E + eb);
            w4 = *(const v4f*)(ew + eb);
        } else {
#pragma unroll
            for (int u = 0; u < 4; ++u) {
                int e = eb + u;
                r4[u] = e < E ? ei[e] : 0;
                c4[u] = e < E ? ei[E + e] : 0;
                w4[u] = e < E ? ew[e] : 0.f;
            }
        }
#pragma unroll
        for (int u = 0; u < 4; ++u) {
            int e = eb + u;
            vd[u] = e < E;
            int bkt = r4[u] >> 6;
            int rl  = r4[u] & (RB - 1);
            int lp = 0;
            if (vd[u]) lp = atomicAdd(&hist[bkt], 1);   // native LDS atomic
            pk[u] = (((unsigned)lp) << 11) | (unsigned)bkt;
            cw[u] = (((ull)__float_as_uint(w4[u])) << 32) |
                    (unsigned)((rl << 17) | c4[u]);
        }
    }
    __syncthreads();

    // one global reservation per (block,bucket); padded counters: each
    // bucket counter owns a full 64B line (no cross-bucket line contention)
    for (int i = t; i < NB; i += 512) {
        int h = hist[i];
        gbase[i] = h ? atomicAdd(&bcnt[i * BPAD], h) : 0;
    }
    __syncthreads();

#pragma unroll
    for (int j = 0; j < 4; ++j) {
        if (!vd[j]) continue;
        int bkt = pk[j] & 2047;
        int pos = gbase[bkt] + (int)(pk[j] >> 11);
        if (pos < CAP) {
            seg[(size_t)bkt * CAP + pos] = cw[j];
        } else {
            int o = atomicAdd(ovf_cnt, 1);
            if (o < OVF_CAP) {
                unsigned lo = (unsigned)cw[j];
                ovf[o] = make_int3((bkt << 6) | ((lo >> 17) & (RB - 1)),
                                   lo & 0x1FFFF, (int)(cw[j] >> 32));
            }
        }
    }
}

// ---------- phase 2: segment -> LDS padded CSR -> register acc -> out ----
// 256 thr (4 waves), 12.3KB LDS, 8 blocks/CU target.
template <bool BF>
__global__ __launch_bounds__(256, 8) void bucket_acc(
    const void* __restrict__ xv, const ull* __restrict__ seg,
    const int* __restrict__ bcnt, float* __restrict__ out,
    int* __restrict__ ovf_cnt, int3* __restrict__ ovf, int N)
{
    __shared__ int      cur[RB];
    __shared__ unsigned tile[RB * SLOTS];   // 12 KB packed col|fp16w
    int t = threadIdx.x;
    int g = blockIdx.x;
    if (t < RB) cur[t] = 0;
    __syncthreads();

    int c = bcnt[g * BPAD];
    if (c > CAP) c = CAP;
    const ull* base = seg + (size_t)g * CAP;

    // build LDS CSR: coalesced seg read, LDS cursor atomic, LDS 4B write
    for (int i = t; i < c; i += 256) {
        ull e = base[i];
        unsigned lo = (unsigned)e;
        int rl  = (lo >> 17) & (RB - 1);
        int col = lo & 0x1FFFF;
        float w = __int_as_float((int)(e >> 32));
        int pos = atomicAdd(&cur[rl], 1);          // native LDS int atomic
        if (pos < SLOTS) {
            tile[rl * SLOTS + pos] = pack_cw(col, w);
        } else {
            int o = atomicAdd(ovf_cnt, 1);
            if (o < OVF_CAP)
                ovf[o] = make_int3(g * RB + rl, col, __float_as_int(w));
        }
    }
    __syncthreads();

    // register accumulation: wave handles 16 rows, 8-deep gathers
    int wid  = t >> 6;
    int lane = t & 63;
    const unsigned short* xh = (const unsigned short*)xv;
    const float*          xf = (const float*)xv;

    for (int k = 0; k < 16; ++k) {
        int r   = wid * 16 + k;
        int row = g * RB + r;
        if (row >= N) break;
        int cc = cur[r];
        if (cc > SLOTS) cc = SLOTS;
        const unsigned* tb = &tile[r * SLOTS];

        float acc = 0.0f;
        int p = 0;
        for (; p + 8 <= cc; p += 8) {
            unsigned a[8]; float xr[8];
#pragma unroll
            for (int i = 0; i < 8; ++i) a[i] = tb[p + i];   // LDS broadcast
#pragma unroll
            for (int i = 0; i < 8; ++i) {
                size_t off = (((size_t)(a[i] >> 15)) << 6) + lane;
                xr[i] = BF ? bf2f(xh[off]) : xf[off];
            }
#pragma unroll
            for (int i = 0; i < 8; ++i)
                acc = fmaf(xr[i], unpack_w(a[i]), acc);
        }
        if (p < cc) {   // masked 8-group tail (cc >= 1 here)
            unsigned a[8]; float xr[8], w[8];
#pragma unroll
            for (int i = 0; i < 8; ++i) {
                int q = p + i;
                bool valid = q < cc;
                if (!valid) q = cc - 1;
                a[i] = tb[q];
                w[i] = valid ? unpack_w(a[i]) : 0.0f;
            }
#pragma unroll
            for (int i = 0; i < 8; ++i) {
                size_t off = (((size_t)(a[i] >> 15)) << 6) + lane;
                xr[i] = BF ? bf2f(xh[off]) : xf[off];
            }
#pragma unroll
            for (int i = 0; i < 8; ++i) acc = fmaf(xr[i], w[i], acc);
        }
        __builtin_nontemporal_store(acc, out + (((size_t)row) << 6) + lane);
    }
}

// ---------- overflow fixup (normally 0 edges) ----------
template <bool BF>
__global__ __launch_bounds__(256) void ovf_apply(
    const void* __restrict__ xv, const int* __restrict__ ovf_cnt,
    const int3* __restrict__ ovf, float* __restrict__ out)
{
    int n = *ovf_cnt;
    if (n > OVF_CAP) n = OVF_CAP;
    int wid  = (blockIdx.x * 256 + threadIdx.x) >> 6;
    int lane = threadIdx.x & 63;
    int nw   = gridDim.x * 4;
    for (int o = wid; o < n; o += nw) {
        int3 tt = ovf[o];
        float w = __int_as_float(tt.z);
        size_t off = (((size_t)tt.y) << 6) + lane;
        float x = BF ? bf2f(((const unsigned short*)xv)[off])
                     : ((const float*)xv)[off];
        atomicAdd(&out[(((size_t)tt.x) << 6) + lane], x * w);
    }
}

// ---------- fallback: direct atomic scatter ----------
__global__ __launch_bounds__(256) void scatter_edges(
    const float* __restrict__ x, const int* __restrict__ ei,
    const float* __restrict__ ew, float* __restrict__ out, int E)
{
    long long idx = (long long)blockIdx.x * 256 + threadIdx.x;
    int e = (int)(idx >> 4);
    if (e >= E) return;
    int j = (int)(idx & 15);
    int row = ei[e];
    int col = ei[E + e];
    float w = ew[e];
    v4f v = *(const v4f*)(x + (((size_t)col) << 6) + (j << 2));
    float* op = out + (((size_t)row) << 6) + (j << 2);
    atomicAdd(op + 0, v.x * w);
    atomicAdd(op + 1, v.y * w);
    atomicAdd(op + 2, v.z * w);
    atomicAdd(op + 3, v.w * w);
}

extern "C" void kernel_launch(void* const* d_in, const int* in_sizes, int n_in,
                              void* d_out, int out_size, void* d_ws, size_t ws_size,
                              hipStream_t stream) {
    const float* x  = (const float*)d_in[0];
    const int*   ei = (const int*)d_in[1];
    const float* ew = (const float*)d_in[2];
    float*       out = (float*)d_out;

    int E = in_sizes[2];
    int N = out_size / 64;
    int NB = (N + RB - 1) / RB;

    // ws (ints): bcnt[NB*BPAD] | ovf_cnt | pad | ovf[3*OVF] | [xb N*32] |
    //            seg[NB*CAP*2]
    size_t ovf_base  = (size_t)NB * BPAD + 2;
    size_t xb_base   = (ovf_base + 3 * (size_t)OVF_CAP + 3) & ~(size_t)3;
    size_t xb_ints   = (size_t)N * 32;
    size_t seg_ints  = (size_t)NB * CAP * 2;

    size_t seg_base_bf = (xb_base + xb_ints + 1) & ~(size_t)1;
    size_t need_bf     = (seg_base_bf + seg_ints) * 4;

    size_t seg_base_f  = (xb_base + 1) & ~(size_t)1;
    size_t need_f      = (seg_base_f + seg_ints) * 4;

    int nbin  = (E + CHUNK - 1) / CHUNK;
    int n4    = (N * 64) / 4;
    int nconv = (n4 + 2047) / 2048;

    if ((ws_size >= need_bf || ws_size >= need_f) && N <= (1 << 17)) {
        bool use_bf = ws_size >= need_bf;
        int* w32 = (int*)d_ws;
        int* bcnt = w32;
        int* ovf_cnt = w32 + NB * BPAD;
        int3* ovf = (int3*)(w32 + ovf_base);
        unsigned short* xb = (unsigned short*)(w32 + xb_base);
        ull* seg = (ull*)(w32 + (use_bf ? seg_base_bf : seg_base_f));

        (void)hipMemsetAsync(w32, 0, ((size_t)NB * BPAD + 2) * sizeof(int),
                             stream);

        if (use_bf) {
            prep<<<nbin + nconv, 512, 0, stream>>>(
                ei, ew, bcnt, seg, ovf_cnt, ovf, E, NB, nbin, x, xb, n4);
            bucket_acc<true><<<NB, 256, 0, stream>>>(
                xb, seg, bcnt, out, ovf_cnt, ovf, N);
            ovf_apply<true><<<64, 256, 0, stream>>>(xb, ovf_cnt, ovf, out);
        } else {
            prep<<<nbin, 512, 0, stream>>>(
                ei, ew, bcnt, seg, ovf_cnt, ovf, E, NB, nbin, x, xb, 0);
            bucket_acc<false><<<NB, 256, 0, stream>>>(
                x, seg, bcnt, out, ovf_cnt, ovf, N);
            ovf_apply<false><<<64, 256, 0, stream>>>(x, ovf_cnt, ovf, out);
        }
    } else {
        (void)hipMemsetAsync(out, 0, (size_t)out_size * sizeof(float), stream);
        long long threads = (long long)E * 16;
        scatter_edges<<<(int)((threads + 255) / 256), 256, 0, stream>>>(
            x, ei, ew, out, E);
    }
}

// Round 6
// 168.314 us; speedup vs baseline: 1.3271x; 1.1650x over previous
//
#include <hip/hip_runtime.h>
#include <hip/hip_fp16.h>
#include <stdint.h>

// LightGCNConv: out[row] += x[col] * edge_weight[e]
// x:[N,64] f32, edge_index:[2,E] int32, edge_weight:[E] f32, out:[N,64] f32.
//
// Pipeline (v6 — LDS counting-sort binning for wave-coalesced seg stores):
//  1) prep: merged {edge binning | x->bf16 convert}. Binning per block
//     (CHUNK=4096): LDS hist+rank -> in-LDS exclusive scan -> place edges
//     bucket-SORTED in LDS with precomputed global positions -> linear
//     sweep store (consecutive lanes write consecutive sorted entries).
//     v1-v5 invariant ~60-70us bin cost was 1.6M wave-scattered 8B stores
//     (64 partial-line L2 RMWs per store instr; prep VALUBusy 2.5%).
//     Sorted sweep makes stores ~full-line.
//  2) bucket_acc: per 128-row bucket (512 thr, 4 blocks/CU): seg ->
//     LDS padded-CSR (native int cursor atomics) -> per-wave REGISTER
//     accumulation of 16 rows, 8-deep pipelined bf16 gathers -> coalesced
//     nontemporal out stores. No global atomics, no out pre-zero.

typedef unsigned long long ull;
typedef int   v4i __attribute__((ext_vector_type(4)));
typedef float v4f __attribute__((ext_vector_type(4)));

#define RB      128      // rows per bucket
#define CAP     2432     // entries per bucket segment; mean 2048 (+8.5 sigma)
#define CHUNK   4096     // edges per bin block (512 thr x 8)
#define EPT     8        // edges per thread
#define SLOTS   48       // padded-CSR slots per row (max expected deg ~36)
#define BPAD    16       // bcnt stride in ints (64B: one counter per line)
#define OVF_CAP 65536
#define NBP     1024     // padded bucket count (N <= 131072 -> NB <= 1024)

__device__ __forceinline__ unsigned short f2bf(float f) {
    union { float f; unsigned int u; } c;
    c.f = f;
    unsigned int lsb = (c.u >> 16) & 1u;
    c.u += 0x7fffu + lsb;
    return (unsigned short)(c.u >> 16);
}
__device__ __forceinline__ float bf2f(unsigned short u) {
    union { unsigned int u; float f; } c;
    c.u = ((unsigned int)u) << 16;
    return c.f;
}
__device__ __forceinline__ unsigned pack_cw(int col, float w) {
    unsigned hb = __half_as_ushort(__float2half(w));
    return (((unsigned)col) << 15) | (hb >> 1);
}
__device__ __forceinline__ float unpack_w(unsigned v) {
    return __half2float(__ushort_as_half((unsigned short)((v & 0x7fffu) << 1)));
}

// ---------- phase 1 (merged): sorted edge binning | x->bf16 convert ------
__global__ __launch_bounds__(512) void prep(
    const int* __restrict__ ei, const float* __restrict__ ew,
    int* __restrict__ bcnt, ull* __restrict__ seg,
    int* __restrict__ ovf_cnt, int3* __restrict__ ovf, int E, int NB,
    int nbin, const float* __restrict__ x, unsigned short* __restrict__ xb,
    int n4)
{
    __shared__ int      hist[NBP];
    __shared__ int      lstart[NBP];
    __shared__ int      gbase[NBP];
    __shared__ int      wsum[8];
    __shared__ ull      sorted[CHUNK];      // 32 KB
    __shared__ unsigned gpos[CHUNK];        // 16 KB
    int t = threadIdx.x;

    if ((int)blockIdx.x >= nbin) {
        // ---- convert part: 4096 v4f per block ----
        int i0 = ((int)blockIdx.x - nbin) * 4096 + t;
#pragma unroll
        for (int k = 0; k < 8; ++k) {
            int i = i0 + k * 512;
            if (i < n4) {
                v4f v = ((const v4f*)x)[i];
                ushort4 o;
                o.x = f2bf(v.x); o.y = f2bf(v.y);
                o.z = f2bf(v.z); o.w = f2bf(v.w);
                ((ushort4*)xb)[i] = o;
            }
        }
        return;
    }

    // ---- bin part ----
    for (int i = t; i < NBP; i += 512) hist[i] = 0;
    __syncthreads();

    int e0   = blockIdx.x * CHUNK;
    int nval = E - e0; if (nval > CHUNK) nval = CHUNK;
    bool al4 = ((E & 3) == 0);

    int      rk[EPT];     // rank within (block,bucket)
    unsigned bk[EPT];     // bucket
    ull      cw[EPT];     // w<<32 | rl<<17 | col
    bool     vd[EPT];
#pragma unroll
    for (int j = 0; j < EPT / 4; ++j) {
        int eb = e0 + (j * 512 + t) * 4;
        v4i r4, c4; v4f w4;
        if (al4 && eb + 3 < E) {
            r4 = *(const v4i*)(ei + eb);
            c4 = *(const v4i*)(ei + E + eb);
            w4 = *(const v4f*)(ew + eb);
        } else {
#pragma unroll
            for (int u = 0; u < 4; ++u) {
                int e = eb + u;
                r4[u] = e < E ? ei[e] : 0;
                c4[u] = e < E ? ei[E + e] : 0;
                w4[u] = e < E ? ew[e] : 0.f;
            }
        }
#pragma unroll
        for (int u = 0; u < 4; ++u) {
            int idx = j * 4 + u;
            int e = eb + u;
            vd[idx] = e < E;
            int bkt = r4[u] >> 7;
            int rl  = r4[u] & (RB - 1);
            rk[idx] = vd[idx] ? atomicAdd(&hist[bkt], 1) : 0;  // LDS native
            bk[idx] = (unsigned)bkt;
            cw[idx] = (((ull)__float_as_uint(w4[u])) << 32) |
                      (unsigned)((rl << 17) | c4[u]);
        }
    }
    __syncthreads();

    // ---- exclusive scan hist[0..NBP) -> lstart (pair + wave + block) ----
    {
        int a = hist[2 * t], b = hist[2 * t + 1];
        int ps = a + b;
        int lane = t & 63, wid = t >> 6;
        int s = ps;
#pragma unroll
        for (int off = 1; off < 64; off <<= 1) {
            int o = __shfl_up(s, off);
            if (lane >= off) s += o;
        }
        if (lane == 63) wsum[wid] = s;
        __syncthreads();
        if (t < 8) {
            int v = wsum[t];
            int s2 = v;
#pragma unroll
            for (int off = 1; off < 8; off <<= 1) {
                int o = __shfl_up(s2, off);
                if (t >= off) s2 += o;
            }
            wsum[t] = s2 - v;    // exclusive wave offset
        }
        __syncthreads();
        int excl = s - ps + wsum[wid];
        lstart[2 * t]     = excl;
        lstart[2 * t + 1] = excl + a;
    }

    // ---- global reservations: one atomic per (block,bucket), padded ----
    for (int i = t; i < NB; i += 512) {
        int h = hist[i];
        gbase[i] = h ? atomicAdd(&bcnt[i * BPAD], h) : 0;
    }
    __syncthreads();

    // ---- pass 2: place edges sorted in LDS + precompute global pos ----
#pragma unroll
    for (int j = 0; j < EPT; ++j) {
        if (!vd[j]) continue;
        int bkt = (int)bk[j];
        int lp  = lstart[bkt] + rk[j];
        sorted[lp] = cw[j];
        int loc = gbase[bkt] + rk[j];
        if (loc < CAP) {
            gpos[lp] = (unsigned)(bkt * CAP + loc);
        } else {
            gpos[lp] = 0xFFFFFFFFu;
            int o = atomicAdd(ovf_cnt, 1);
            if (o < OVF_CAP) {
                unsigned lo = (unsigned)cw[j];
                ovf[o] = make_int3(bkt * RB + ((lo >> 17) & (RB - 1)),
                                   lo & 0x1FFFF, (int)(cw[j] >> 32));
            }
        }
    }
    __syncthreads();

    // ---- pass 3: wave-coalesced sweep store ----
    for (int i = t; i < nval; i += 512) {
        unsigned gp = gpos[i];
        if (gp != 0xFFFFFFFFu) seg[gp] = sorted[i];
    }
}

// ---------- phase 2: segment -> LDS padded CSR -> register acc -> out ----
// 512 thr (8 waves), ~24.5 KB LDS, 4 blocks/CU (thread-capped).
template <bool BF>
__global__ __launch_bounds__(512, 8) void bucket_acc(
    const void* __restrict__ xv, const ull* __restrict__ seg,
    const int* __restrict__ bcnt, float* __restrict__ out,
    int* __restrict__ ovf_cnt, int3* __restrict__ ovf, int N)
{
    __shared__ int      cur[RB];
    __shared__ unsigned tile[RB * SLOTS];   // 24 KB packed col|fp16w
    int t = threadIdx.x;
    int g = blockIdx.x;
    if (t < RB) cur[t] = 0;
    __syncthreads();

    int c = bcnt[g * BPAD];
    if (c > CAP) c = CAP;
    const ull* base = seg + (size_t)g * CAP;

    // build LDS CSR: coalesced seg read, LDS cursor atomic, LDS 4B write
    for (int i = t; i < c; i += 512) {
        ull e = base[i];
        unsigned lo = (unsigned)e;
        int rl  = (lo >> 17) & (RB - 1);
        int col = lo & 0x1FFFF;
        float w = __int_as_float((int)(e >> 32));
        int pos = atomicAdd(&cur[rl], 1);          // native LDS int atomic
        if (pos < SLOTS) {
            tile[rl * SLOTS + pos] = pack_cw(col, w);
        } else {
            int o = atomicAdd(ovf_cnt, 1);
            if (o < OVF_CAP)
                ovf[o] = make_int3(g * RB + rl, col, __float_as_int(w));
        }
    }
    __syncthreads();

    // register accumulation: each wave handles 16 rows, 8-deep gathers
    int wid  = t >> 6;
    int lane = t & 63;
    const unsigned short* xh = (const unsigned short*)xv;
    const float*          xf = (const float*)xv;

    for (int k = 0; k < 16; ++k) {
        int r   = wid * 16 + k;
        int row = g * RB + r;
        if (row >= N) break;
        int cc = cur[r];
        if (cc > SLOTS) cc = SLOTS;
        const unsigned* tb = &tile[r * SLOTS];

        float acc = 0.0f;
        int p = 0;
        for (; p + 8 <= cc; p += 8) {
            unsigned a[8]; float xr[8];
#pragma unroll
            for (int i = 0; i < 8; ++i) a[i] = tb[p + i];   // LDS broadcast
#pragma unroll
            for (int i = 0; i < 8; ++i) {
                size_t off = (((size_t)(a[i] >> 15)) << 6) + lane;
                xr[i] = BF ? bf2f(xh[off]) : xf[off];
            }
#pragma unroll
            for (int i = 0; i < 8; ++i)
                acc = fmaf(xr[i], unpack_w(a[i]), acc);
        }
        if (p < cc) {   // masked 8-group tail (cc >= 1 here)
            unsigned a[8]; float xr[8], w[8];
#pragma unroll
            for (int i = 0; i < 8; ++i) {
                int q = p + i;
                bool valid = q < cc;
                if (!valid) q = cc - 1;
                a[i] = tb[q];
                w[i] = valid ? unpack_w(a[i]) : 0.0f;
            }
#pragma unroll
            for (int i = 0; i < 8; ++i) {
                size_t off = (((size_t)(a[i] >> 15)) << 6) + lane;
                xr[i] = BF ? bf2f(xh[off]) : xf[off];
            }
#pragma unroll
            for (int i = 0; i < 8; ++i) acc = fmaf(xr[i], w[i], acc);
        }
        __builtin_nontemporal_store(acc, out + (((size_t)row) << 6) + lane);
    }
}

// ---------- overflow fixup (normally 0 edges) ----------
template <bool BF>
__global__ __launch_bounds__(256) void ovf_apply(
    const void* __restrict__ xv, const int* __restrict__ ovf_cnt,
    const int3* __restrict__ ovf, float* __restrict__ out)
{
    int n = *ovf_cnt;
    if (n > OVF_CAP) n = OVF_CAP;
    int wid  = (blockIdx.x * 256 + threadIdx.x) >> 6;
    int lane = threadIdx.x & 63;
    int nw   = gridDim.x * 4;
    for (int o = wid; o < n; o += nw) {
        int3 tt = ovf[o];
        float w = __int_as_float(tt.z);
        size_t off = (((size_t)tt.y) << 6) + lane;
        float x = BF ? bf2f(((const unsigned short*)xv)[off])
                     : ((const float*)xv)[off];
        atomicAdd(&out[(((size_t)tt.x) << 6) + lane], x * w);
    }
}

// ---------- fallback: direct atomic scatter ----------
__global__ __launch_bounds__(256) void scatter_edges(
    const float* __restrict__ x, const int* __restrict__ ei,
    const float* __restrict__ ew, float* __restrict__ out, int E)
{
    long long idx = (long long)blockIdx.x * 256 + threadIdx.x;
    int e = (int)(idx >> 4);
    if (e >= E) return;
    int j = (int)(idx & 15);
    int row = ei[e];
    int col = ei[E + e];
    float w = ew[e];
    v4f v = *(const v4f*)(x + (((size_t)col) << 6) + (j << 2));
    float* op = out + (((size_t)row) << 6) + (j << 2);
    atomicAdd(op + 0, v.x * w);
    atomicAdd(op + 1, v.y * w);
    atomicAdd(op + 2, v.z * w);
    atomicAdd(op + 3, v.w * w);
}

extern "C" void kernel_launch(void* const* d_in, const int* in_sizes, int n_in,
                              void* d_out, int out_size, void* d_ws, size_t ws_size,
                              hipStream_t stream) {
    const float* x  = (const float*)d_in[0];
    const int*   ei = (const int*)d_in[1];
    const float* ew = (const float*)d_in[2];
    float*       out = (float*)d_out;

    int E = in_sizes[2];
    int N = out_size / 64;
    int NB = (N + RB - 1) / RB;

    // ws (ints): bcnt[NB*BPAD] | ovf_cnt | pad | ovf[3*OVF] | [xb N*32] |
    //            seg[NB*CAP*2]
    size_t ovf_base  = (size_t)NB * BPAD + 2;
    size_t xb_base   = (ovf_base + 3 * (size_t)OVF_CAP + 3) & ~(size_t)3;
    size_t xb_ints   = (size_t)N * 32;
    size_t seg_ints  = (size_t)NB * CAP * 2;

    size_t seg_base_bf = (xb_base + xb_ints + 1) & ~(size_t)1;
    size_t need_bf     = (seg_base_bf + seg_ints) * 4;

    size_t seg_base_f  = (xb_base + 1) & ~(size_t)1;
    size_t need_f      = (seg_base_f + seg_ints) * 4;

    int nbin  = (E + CHUNK - 1) / CHUNK;
    int n4    = (N * 64) / 4;
    int nconv = (n4 + 4095) / 4096;

    if ((ws_size >= need_bf || ws_size >= need_f) && N <= (1 << 17)) {
        bool use_bf = ws_size >= need_bf;
        int* w32 = (int*)d_ws;
        int* bcnt = w32;
        int* ovf_cnt = w32 + NB * BPAD;
        int3* ovf = (int3*)(w32 + ovf_base);
        unsigned short* xb = (unsigned short*)(w32 + xb_base);
        ull* seg = (ull*)(w32 + (use_bf ? seg_base_bf : seg_base_f));

        (void)hipMemsetAsync(w32, 0, ((size_t)NB * BPAD + 2) * sizeof(int),
                             stream);

        if (use_bf) {
            prep<<<nbin + nconv, 512, 0, stream>>>(
                ei, ew, bcnt, seg, ovf_cnt, ovf, E, NB, nbin, x, xb, n4);
            bucket_acc<true><<<NB, 512, 0, stream>>>(
                xb, seg, bcnt, out, ovf_cnt, ovf, N);
            ovf_apply<true><<<64, 256, 0, stream>>>(xb, ovf_cnt, ovf, out);
        } else {
            prep<<<nbin, 512, 0, stream>>>(
                ei, ew, bcnt, seg, ovf_cnt, ovf, E, NB, nbin, x, xb, 0);
            bucket_acc<false><<<NB, 512, 0, stream>>>(
                x, seg, bcnt, out, ovf_cnt, ovf, N);
            ovf_apply<false><<<64, 256, 0, stream>>>(x, ovf_cnt, ovf, out);
        }
    } else {
        (void)hipMemsetAsync(out, 0, (size_t)out_size * sizeof(float), stream);
        long long threads = (long long)E * 16;
        scatter_edges<<<(int)((threads + 255) / 256), 256, 0, stream>>>(
            x, ei, ew, out, E);
    }
}